// Round 5
// baseline (236.631 us; speedup 1.0000x reference)
//
#include <hip/hip_runtime.h>
#include <math.h>

// LorentzNotGroupNorm, MI355X. x:(64,3136,128) fp32, groups=8.
// Group = 8 consecutive pixels x 128 ch = 4KB; one wave per group-slot.
// lane = 8*p + q: pixel p (0..7), channel block q (0..7), 16 ch/lane.
//
// K1 (2 groups/wave, 12544 waves): centroid via fold+LDS, x_T scalars
//     (sc,k,coef) with x_T = sc*y + k*avg + coef*e0, ||x_T|| from reduced
//     scalars. Spills avg[128]/group, scal float4/(g,p), and per-wave norm
//     partial (2 groups, same batch since 2|392).
// K2 (4 consecutive groups/wave, 6272 waves, same batch since 4|392):
//     gathers 196 partials -> var, then epilogue only: u = xt*gm/(var+eps),
//     max-euclid rescale, transp0(beta), expmap(beta). No LDS, one rsum8x2
//     chain per group.

constexpr int S_GROUPS = 392;
constexpr int N_GROUPS = 64 * S_GROUPS;   // 25088
constexpr int PART = S_GROUPS / 2;        // 196 per-wave partials per batch

__device__ __forceinline__ void wave_lds_fence() {
  __asm__ volatile("" ::: "memory");
  __builtin_amdgcn_wave_barrier();
  __asm__ volatile("" ::: "memory");
}

__device__ __forceinline__ void load16(float d[16], const float* __restrict__ s) {
#pragma unroll
  for (int j = 0; j < 4; ++j)
    *reinterpret_cast<float4*>(&d[4 * j]) =
        *reinterpret_cast<const float4*>(s + 4 * j);
}

__device__ __forceinline__ void store16(float* __restrict__ d, const float s[16]) {
#pragma unroll
  for (int j = 0; j < 4; ++j)
    *reinterpret_cast<float4*>(d + 4 * j) =
        *reinterpret_cast<const float4*>(&s[4 * j]);
}

__device__ __forceinline__ void rsum8x3(float& a, float& b, float& c) {
#pragma unroll
  for (int m = 1; m <= 4; m <<= 1) {
    a += __shfl_xor(a, m, 64);
    b += __shfl_xor(b, m, 64);
    c += __shfl_xor(c, m, 64);
  }
}

__device__ __forceinline__ void rsum8x2(float& a, float& b) {
#pragma unroll
  for (int m = 1; m <= 4; m <<= 1) {
    a += __shfl_xor(a, m, 64);
    b += __shfl_xor(b, m, 64);
  }
}

__device__ __forceinline__ float rsum8(float a) {
#pragma unroll
  for (int m = 1; m <= 4; m <<= 1) a += __shfl_xor(a, m, 64);
  return a;
}

// Pixel-mean fold over lane bits {32,16,8}; lane (p,q) ends with mean
// channels {16q+2p, 16q+2p+1} in (c0,c1).
__device__ __forceinline__ void fold_mean(const float v[16], int lane,
                                          float& c0, float& c1) {
  float a8[8];
  const bool h5 = (lane & 32) != 0;
#pragma unroll
  for (int i = 0; i < 8; ++i) {
    float kp = h5 ? v[i + 8] : v[i];
    float sd = h5 ? v[i] : v[i + 8];
    a8[i] = kp + __shfl_xor(sd, 32, 64);
  }
  float a4[4];
  const bool h4 = (lane & 16) != 0;
#pragma unroll
  for (int i = 0; i < 4; ++i) {
    float kp = h4 ? a8[i + 4] : a8[i];
    float sd = h4 ? a8[i] : a8[i + 4];
    a4[i] = kp + __shfl_xor(sd, 16, 64);
  }
  const bool h3 = (lane & 8) != 0;
  float kp0 = h3 ? a4[2] : a4[0], sd0 = h3 ? a4[0] : a4[2];
  float kp1 = h3 ? a4[3] : a4[1], sd1 = h3 ? a4[1] : a4[3];
  c0 = (kp0 + __shfl_xor(sd0, 8, 64)) * 0.125f;
  c1 = (kp1 + __shfl_xor(sd1, 8, 64)) * 0.125f;
}

struct CoreOut {
  float avg[16];
  float sc, k, coef;
  float iaL, dpL, yyE, y0p, avg0;
};

__device__ __forceinline__ void core(const float v[16], int lane,
                                     float* __restrict__ smrow, CoreOut& o) {
  const int p = lane >> 3, q = lane & 7;
  float c0, c1;
  fold_mean(v, lane, c0, c1);
  *reinterpret_cast<float2*>(&smrow[q * 16 + p * 2]) = make_float2(c0, c1);
  wave_lds_fence();
#pragma unroll
  for (int j = 0; j < 4; ++j)
    *reinterpret_cast<float4*>(&o.avg[4 * j]) =
        *reinterpret_cast<const float4*>(&smrow[q * 16 + 4 * j]);
  wave_lds_fence();

  float pa = 0.f, pd = 0.f, py = 0.f;
#pragma unroll
  for (int i = 0; i < 16; ++i) {
    pa = fmaf(o.avg[i], o.avg[i], pa);   // -> <avg,avg>_L
    pd = fmaf(o.avg[i], v[i], pd);       // -> <avg,y>_L
    py = fmaf(v[i], v[i], py);           // -> ||y||^2_E
  }
  if (q == 0) {
    pa -= 2.f * o.avg[0] * o.avg[0];
    pd -= 2.f * o.avg[0] * v[0];
  }
  rsum8x3(pa, pd, py);
  o.iaL = pa;
  o.dpL = pd;
  o.yyE = py;
  o.y0p = __shfl(v[0], lane & 56, 64);
  o.avg0 = __shfl(o.avg[0], 0, 64);

  float rden = rsqrtf(fmaxf(-pa, 1e-8f));
  float a_raw = -pd * rden;
  float alpha = fmaxf(a_raw, 1.f + 1e-7f);
  float t = alpha - 1.f;
  float dist = log1pf(t + sqrtf(t * (alpha + 1.f)));   // arccosh(alpha)
  float yyL = py - 2.f * o.y0p * o.y0p;
  float inn = fmaxf(yyL + 2.f * alpha * a_raw - alpha * alpha, 1e-8f);
  o.sc = dist * rsqrtf(inn);
  float am = alpha * rden;
  float mean0 = rden * o.avg0;
  float v0 = o.sc * (o.y0p - am * o.avg0);
  o.coef = -v0 / (1.f + mean0);
  o.k = o.coef * rden - o.sc * am;
}

__device__ __forceinline__ float xt_norm(const CoreOut& A) {
  float yavgE = A.dpL + 2.f * A.avg0 * A.y0p;
  float aaE = A.iaL + 2.f * A.avg0 * A.avg0;
  float nsq = A.sc * A.sc * A.yyE + A.k * A.k * aaE + 2.f * A.sc * A.k * yavgE +
              A.coef * A.coef + 2.f * A.coef * (A.sc * A.y0p + A.k * A.avg0);
  return sqrtf(fmaxf(nsq, 0.f));
}

__global__ __launch_bounds__(256) void lngn_k1(const float* __restrict__ x,
                                               float* __restrict__ var_part,
                                               float* __restrict__ scal,
                                               float* __restrict__ avg_ws) {
  __shared__ float sm[4][2][128];
  const int w = threadIdx.x >> 6, lane = threadIdx.x & 63;
  const int p = lane >> 3, q = lane & 7;
  const int off = p * 128 + q * 16;
  const int wid = blockIdx.x * 4 + w;
  const int g0 = wid * 2;                       // 2 consecutive groups, same b
  const float* b0 = x + (size_t)g0 * 1024 + off;
  float vA[16], vB[16];
  load16(vA, b0);
  load16(vB, b0 + 1024);
  CoreOut A, B;
  core(vA, lane, sm[w][0], A);
  core(vB, lane, sm[w][1], B);
  if (q == 0) {
    *reinterpret_cast<float4*>(&scal[((size_t)g0 * 8 + p) * 4]) =
        make_float4(A.sc, A.k, A.coef, 0.f);
    *reinterpret_cast<float4*>(&scal[((size_t)(g0 + 1) * 8 + p) * 4]) =
        make_float4(B.sc, B.k, B.coef, 0.f);
    var_part[(size_t)wid * 8 + p] = xt_norm(A) + xt_norm(B);
  }
  if (p == 0) {
    store16(avg_ws + (size_t)g0 * 128 + q * 16, A.avg);
    store16(avg_ws + (size_t)(g0 + 1) * 128 + q * 16, B.avg);
  }
}

__global__ __launch_bounds__(256) void lngn_k2(
    const float* __restrict__ x, const float* __restrict__ gamma,
    const float* __restrict__ beta, const float* __restrict__ var_part,
    const float* __restrict__ scal, const float* __restrict__ avg_ws,
    float* __restrict__ out) {
  const int w = threadIdx.x >> 6, lane = threadIdx.x & 63;
  const int p = lane >> 3, q = lane & 7;
  const int off = p * 128 + q * 16;
  const int wid = blockIdx.x * 4 + w;
  const int b = wid / 98;  // 4 consecutive groups/wave; 392/4=98 waves/batch

  // var gather: sum var_part[b][s][p] over s (lane q takes s = q, q+8, ...)
  float vs = 0.f;
  const float* vp = var_part + (size_t)b * PART * 8 + p;
  for (int s = q; s < PART; s += 8) vs += vp[(size_t)s * 8];
  vs = rsum8(vs);  // all lanes of p-row now hold sum over 196 partials
  const float s1 = 1.f / (vs * (1.f / (float)S_GROUPS) + 1e-5f);

  float gm[16], bt[16];
  load16(gm, gamma + q * 16);
  load16(bt, beta + q * 16);
  float pbb = 0.f;
#pragma unroll
  for (int i = 0; i < 16; ++i) pbb = fmaf(bt[i], bt[i], pbb);
  if (q == 0) pbb -= 2.f * bt[0] * bt[0];
  const float pbbL = rsum8(pbb);                    // <beta,beta>_L
  const float bt0 = __shfl(bt[0], 0, 64);
  const float kk = pbbL - 2.f * bt0 - 1.f;          // <beta+e0,beta+e0>_L
  const float ibt = 1.f / (1.f + bt0);

  size_t g = (size_t)wid * 4;
  float v[16];
  load16(v, x + g * 1024 + off);
  for (int it = 0; it < 4; ++it) {
    float vn[16];
    if (it < 3) load16(vn, x + (g + 1) * 1024 + off);
    float av[16];
    load16(av, avg_ws + g * 128 + q * 16);
    const float4 sck =
        *reinterpret_cast<const float4*>(&scal[(g * 8 + p) * 4]);

    float u[16];
    float pe = 0.f, pb = 0.f;
#pragma unroll
    for (int i = 0; i < 16; ++i) {
      float xt = fmaf(sck.x, v[i], sck.y * av[i]);
      if (i == 0) xt += (q == 0) ? sck.z : 0.f;
      u[i] = xt * (gm[i] * s1);
      pe = fmaf(u[i], u[i], pe);     // ||u||^2_E
      pb = fmaf(bt[i], u[i], pb);    // -> <beta,u>_L
    }
    if (q == 0) pb -= 2.f * bt[0] * u[0];
    rsum8x2(pe, pb);

    float n = sqrtf(pe);
    float scl = fminf(1.f, 10.f / fmaxf(n, 1e-8f));   // max-euclid rescale
    float c2 = scl * pb * ibt;                        // transp0 coefficient
    // u time-comp ~ 0 (tangent at origin), so <u,u>_L ~ pe, <u,beta+e0>_L ~ pb
    float innw = scl * scl * pe + 2.f * scl * c2 * pb + c2 * c2 * kk;
    float nrm = sqrtf(fmaxf(innw, 1e-8f));
    float e = expf(nrm), ie = 1.f / e;
    float chv = 0.5f * (e + ie);
    float isn = (0.5f * (e - ie)) / nrm;
    float C1 = chv + isn * c2, C2 = isn * scl, C3 = isn * c2;
#pragma unroll
    for (int i = 0; i < 16; ++i) u[i] = fmaf(C1, bt[i], C2 * u[i]);
    if (q == 0) u[0] += C3;
    store16(out + g * 1024 + off, u);

    if (it < 3) {
#pragma unroll
      for (int i = 0; i < 16; ++i) v[i] = vn[i];
    }
    ++g;
  }
}

extern "C" void kernel_launch(void* const* d_in, const int* in_sizes, int n_in,
                              void* d_out, int out_size, void* d_ws,
                              size_t ws_size, hipStream_t stream) {
  const float* x = (const float*)d_in[0];
  const float* gamma = (const float*)d_in[1];
  const float* beta = (const float*)d_in[2];
  float* out = (float*)d_out;

  float* var_part = (float*)d_ws;                        // 12544*8   floats
  float* scal = var_part + (size_t)(N_GROUPS / 2) * 8;   // 25088*32  floats
  float* avg_ws = scal + (size_t)N_GROUPS * 32;          // 25088*128 floats

  lngn_k1<<<N_GROUPS / 8, 256, 0, stream>>>(x, var_part, scal, avg_ws);
  lngn_k2<<<N_GROUPS / 16, 256, 0, stream>>>(x, gamma, beta, var_part, scal,
                                             avg_ws, out);
}